// Round 6
// baseline (428.991 us; speedup 1.0000x reference)
//
#include <hip/hip_runtime.h>
#include <math.h>

#define B_   4
#define S_   2048
#define AD   128
#define NH   4
#define HD   32
#define TK   32
#define SEG  1048576            /* 8192*128 */
#define CAP  192                /* survivor capacity per row */

#define OFF_PROJ 0
#define OFF_Q    (1 * SEG)
#define OFF_K    (2 * SEG)
#define OFF_V    (3 * SEG)
#define OFF_ATT  (4 * SEG)
#define OFF_T    (5 * SEG)
#define OFF_SB   (6 * SEG)
#define OFF_CAT  (7 * SEG)      /* 2*SEG floats */

__device__ float g_ws[9 * SEG];
__device__ float g_sc[8 * S_ * S_];   /* 128 MB score chunk, reused per branch */

__device__ __forceinline__ unsigned f2key(float s) {
    unsigned u = __float_as_uint(s);
    return (u & 0x80000000u) ? ~u : (u | 0x80000000u);
}
__device__ __forceinline__ float key2f(unsigned k) {
    unsigned u = (k & 0x80000000u) ? (k & 0x7FFFFFFFu) : ~k;
    return __uint_as_float(u);
}

// Y[M x 128] = X[M x KD] @ W[128 x KD]^T + b.  Pad 72: 4*72%32==8 -> 2-way
// staging writes (free), b128 reads stay 16B-aligned.
template <int KD>
__global__ __launch_bounds__(256)
void lin_kernel(const float* __restrict__ Xext, int xoff,
                const float* __restrict__ W, const float* __restrict__ Bv,
                int yoff)
{
    const float* X = Xext ? Xext : (const float*)(g_ws + xoff);
    float* Y = g_ws + yoff;
    __shared__ float Xs[32][72];
    __shared__ float Ws[32][72];
    const int bm = blockIdx.x * 64;
    const int bn = blockIdx.y * 64;
    const int t  = threadIdx.x;
    const int tx = t & 15, ty = t >> 4;
    const int sr = t >> 3, sc4 = t & 7;
    float acc[4][4] = {};
    for (int kk = 0; kk < KD; kk += 32) {
        #pragma unroll
        for (int it = 0; it < 2; ++it) {
            int rr = sr + it * 32;
            float4 xa = *(const float4*)(X + (size_t)(bm + rr) * KD + kk + sc4 * 4);
            float4 wa = *(const float4*)(W + (size_t)(bn + rr) * KD + kk + sc4 * 4);
            Xs[sc4*4+0][rr] = xa.x; Xs[sc4*4+1][rr] = xa.y;
            Xs[sc4*4+2][rr] = xa.z; Xs[sc4*4+3][rr] = xa.w;
            Ws[sc4*4+0][rr] = wa.x; Ws[sc4*4+1][rr] = wa.y;
            Ws[sc4*4+2][rr] = wa.z; Ws[sc4*4+3][rr] = wa.w;
        }
        __syncthreads();
        #pragma unroll
        for (int kc = 0; kc < 32; ++kc) {
            float4 a4 = *(const float4*)&Xs[kc][ty * 4];
            float4 b4 = *(const float4*)&Ws[kc][tx * 4];
            float a[4] = {a4.x, a4.y, a4.z, a4.w};
            float bb[4] = {b4.x, b4.y, b4.z, b4.w};
            #pragma unroll
            for (int i = 0; i < 4; ++i)
                #pragma unroll
                for (int j = 0; j < 4; ++j)
                    acc[i][j] = fmaf(a[i], bb[j], acc[i][j]);
        }
        __syncthreads();
    }
    #pragma unroll
    for (int i = 0; i < 4; ++i) {
        int row = bm + ty * 4 + i;
        int col = bn + tx * 4;
        float4 o;
        o.x = acc[i][0] + Bv[col + 0]; o.y = acc[i][1] + Bv[col + 1];
        o.z = acc[i][2] + Bv[col + 2]; o.w = acc[i][3] + Bv[col + 3];
        *(float4*)(Y + (size_t)row * AD + col) = o;
    }
}

// Up to three GEMMs sharing one X, selected by blockIdx.z.
template <int KD>
__global__ __launch_bounds__(256)
void lin3_kernel(int xoff,
                 const float* __restrict__ W0, const float* __restrict__ B0, int y0,
                 const float* __restrict__ W1, const float* __restrict__ B1, int y1,
                 const float* __restrict__ W2, const float* __restrict__ B2, int y2)
{
    const int z = blockIdx.z;
    const float* X = (const float*)(g_ws + xoff);
    const float* W = (z == 0) ? W0 : (z == 1) ? W1 : W2;
    const float* Bv = (z == 0) ? B0 : (z == 1) ? B1 : B2;
    float* Y = g_ws + ((z == 0) ? y0 : (z == 1) ? y1 : y2);
    __shared__ float Xs[32][72];
    __shared__ float Ws[32][72];
    const int bm = blockIdx.x * 64;
    const int bn = blockIdx.y * 64;
    const int t  = threadIdx.x;
    const int tx = t & 15, ty = t >> 4;
    const int sr = t >> 3, sc4 = t & 7;
    float acc[4][4] = {};
    for (int kk = 0; kk < KD; kk += 32) {
        #pragma unroll
        for (int it = 0; it < 2; ++it) {
            int rr = sr + it * 32;
            float4 xa = *(const float4*)(X + (size_t)(bm + rr) * KD + kk + sc4 * 4);
            float4 wa = *(const float4*)(W + (size_t)(bn + rr) * KD + kk + sc4 * 4);
            Xs[sc4*4+0][rr] = xa.x; Xs[sc4*4+1][rr] = xa.y;
            Xs[sc4*4+2][rr] = xa.z; Xs[sc4*4+3][rr] = xa.w;
            Ws[sc4*4+0][rr] = wa.x; Ws[sc4*4+1][rr] = wa.y;
            Ws[sc4*4+2][rr] = wa.z; Ws[sc4*4+3][rr] = wa.w;
        }
        __syncthreads();
        #pragma unroll
        for (int kc = 0; kc < 32; ++kc) {
            float4 a4 = *(const float4*)&Xs[kc][ty * 4];
            float4 b4 = *(const float4*)&Ws[kc][tx * 4];
            float a[4] = {a4.x, a4.y, a4.z, a4.w};
            float bb[4] = {b4.x, b4.y, b4.z, b4.w};
            #pragma unroll
            for (int i = 0; i < 4; ++i)
                #pragma unroll
                for (int j = 0; j < 4; ++j)
                    acc[i][j] = fmaf(a[i], bb[j], acc[i][j]);
        }
        __syncthreads();
    }
    #pragma unroll
    for (int i = 0; i < 4; ++i) {
        int row = bm + ty * 4 + i;
        int col = bn + tx * 4;
        float4 o;
        o.x = acc[i][0] + Bv[col + 0]; o.y = acc[i][1] + Bv[col + 1];
        o.z = acc[i][2] + Bv[col + 2]; o.w = acc[i][3] + Bv[col + 3];
        *(float4*)(Y + (size_t)row * AD + col) = o;
    }
}

// scores[zh][q][k] = scale * Q[q]·K[k] for head hh = chunk*8 + zh (K-dim = 32).
__global__ __launch_bounds__(256)
void score_kernel(int qoff, int koff, int chunk)
{
    const int zh = blockIdx.z;
    const int hh = chunk * 8 + zh, b = hh >> 2, h = hh & 3;
    const float* Qb = g_ws + qoff + (size_t)b * S_ * AD + h * HD;
    const float* Kb = g_ws + koff + (size_t)b * S_ * AD + h * HD;
    float* Sc = g_sc + (size_t)zh * S_ * S_;
    __shared__ float Qs[32][72];
    __shared__ float Ks[32][72];
    const int t = threadIdx.x, tx = t & 15, ty = t >> 4;
    const int sr = t >> 3, sc4 = t & 7;
    const int q0 = blockIdx.y * 64, k0 = blockIdx.x * 64;
    #pragma unroll
    for (int it = 0; it < 2; ++it) {
        int rr = sr + it * 32;
        float4 qa = *(const float4*)(Qb + (size_t)(q0 + rr) * AD + sc4 * 4);
        float4 ka = *(const float4*)(Kb + (size_t)(k0 + rr) * AD + sc4 * 4);
        Qs[sc4*4+0][rr] = qa.x; Qs[sc4*4+1][rr] = qa.y;
        Qs[sc4*4+2][rr] = qa.z; Qs[sc4*4+3][rr] = qa.w;
        Ks[sc4*4+0][rr] = ka.x; Ks[sc4*4+1][rr] = ka.y;
        Ks[sc4*4+2][rr] = ka.z; Ks[sc4*4+3][rr] = ka.w;
    }
    __syncthreads();
    float acc[4][4] = {};
    #pragma unroll
    for (int kc = 0; kc < 32; ++kc) {
        float4 a4 = *(const float4*)&Qs[kc][ty * 4];
        float4 b4 = *(const float4*)&Ks[kc][tx * 4];
        float a[4] = {a4.x, a4.y, a4.z, a4.w};
        float bb[4] = {b4.x, b4.y, b4.z, b4.w};
        #pragma unroll
        for (int i = 0; i < 4; ++i)
            #pragma unroll
            for (int j = 0; j < 4; ++j)
                acc[i][j] = fmaf(a[i], bb[j], acc[i][j]);
    }
    const float scale = 0.17677669529663688f;  // 1/sqrt(32)
    #pragma unroll
    for (int i = 0; i < 4; ++i) {
        float4 o;
        o.x = acc[i][0] * scale; o.y = acc[i][1] * scale;
        o.z = acc[i][2] * scale; o.w = acc[i][3] * scale;
        *(float4*)(Sc + (size_t)(q0 + ty * 4 + i) * S_ + k0 + tx * 4) = o;
    }
}

// Exact top-32 of one score row: threshold-prefilter + rank-by-count.
// Selected SET == lax.top_k set (output is an order-independent sum).
__device__ __forceinline__ void select_row(const unsigned (&keys)[32],
                                           unsigned long long* sv,
                                           float* wp, unsigned* jp,
                                           int lane, unsigned thr, float Mf)
{
    // ---- ballot-compact survivors (keys >= thr); j(t)=(t>>2)*256+lane*4+(t&3)
    int base = 0;
    const unsigned long long lt = (1ull << lane) - 1ull;
    #pragma unroll
    for (int t = 0; t < 32; ++t) {
        bool pred = keys[t] >= thr;
        unsigned long long m = __ballot(pred);
        int slot = base + __popcll(m & lt);
        if (pred && slot < CAP) {
            unsigned jidx = (unsigned)((t >> 2) * 256 + lane * 4 + (t & 3));
            sv[slot] = ((unsigned long long)keys[t] << 32) | (unsigned)(2047 - jidx);
        }
        base += __popcll(m);
    }
    const int S = base;
    asm volatile("s_waitcnt lgkmcnt(0)" ::: "memory");

    if (S <= 64) {
        unsigned long long pi = (lane < S) ? sv[lane] : 0ull;
        int rank = 0;
        for (int jx = 0; jx < S; ++jx)
            rank += (sv[jx] > pi) ? 1 : 0;
        float e = 0.f; unsigned ji = 0;
        if (lane < S && rank < TK) {
            float val = key2f((unsigned)(pi >> 32));
            e = __expf(val - Mf);
            ji = 2047u - (unsigned)(pi & 0xFFFFFFFFull);
        }
        float esum = e;
        #pragma unroll
        for (int off = 1; off < 64; off <<= 1) esum += __shfl_xor(esum, off);
        if (lane < S && rank < TK) { wp[rank] = e / esum; jp[rank] = ji; }
    } else if (S <= CAP) {
        unsigned long long pi[3]; int rk[3]; float ee[3]; unsigned jj[3];
        float esum = 0.f;
        #pragma unroll
        for (int u = 0; u < 3; ++u) {
            int i = lane + u * 64;
            pi[u] = (i < S) ? sv[i] : 0ull;
            rk[u] = 0; ee[u] = 0.f; jj[u] = 0;
        }
        for (int jx = 0; jx < S; ++jx) {
            unsigned long long pj = sv[jx];
            #pragma unroll
            for (int u = 0; u < 3; ++u)
                rk[u] += (pj > pi[u]) ? 1 : 0;
        }
        #pragma unroll
        for (int u = 0; u < 3; ++u) {
            int i = lane + u * 64;
            if (i < S && rk[u] < TK) {
                float val = key2f((unsigned)(pi[u] >> 32));
                ee[u] = __expf(val - Mf);
                jj[u] = 2047u - (unsigned)(pi[u] & 0xFFFFFFFFull);
                esum += ee[u];
            }
        }
        #pragma unroll
        for (int off = 1; off < 64; off <<= 1) esum += __shfl_xor(esum, off);
        #pragma unroll
        for (int u = 0; u < 3; ++u) {
            int i = lane + u * 64;
            if (i < S && rk[u] < TK) { wp[rk[u]] = ee[u] / esum; jp[rk[u]] = jj[u]; }
        }
    } else {
        // exact fallback: iterative argmax (value desc, idx asc)
        unsigned consumed = 0u;
        for (int i = 0; i < TK; ++i) {
            unsigned bk = 0u; unsigned gj = 0xFFFFFFFFu;
            #pragma unroll
            for (int t = 0; t < 32; ++t) {
                if (((consumed >> t) & 1u) == 0u) {
                    unsigned kk = keys[t];
                    unsigned j = (unsigned)((t >> 2) * 256 + lane * 4 + (t & 3));
                    if (kk > bk || (kk == bk && j < gj)) { bk = kk; gj = j; }
                }
            }
            #pragma unroll
            for (int off = 1; off < 64; off <<= 1) {
                unsigned ok = (unsigned)__shfl_xor((int)bk, off);
                unsigned oj = (unsigned)__shfl_xor((int)gj, off);
                if (ok > bk || (ok == bk && oj < gj)) { bk = ok; gj = oj; }
            }
            if (((gj >> 2) & 63u) == (unsigned)lane && gj != 0xFFFFFFFFu) {
                int t = ((int)gj >> 8) * 4 + ((int)gj & 3);
                consumed |= (1u << t);
            }
            if (lane == 0) { wp[i] = key2f(bk); jp[i] = gj; }
        }
        asm volatile("s_waitcnt lgkmcnt(0)" ::: "memory");
        float v = (lane < TK) ? wp[lane] : 0.f;
        float e = (lane < TK) ? __expf(v - Mf) : 0.f;
        float esum = e;
        #pragma unroll
        for (int off = 1; off < 64; off <<= 1) esum += __shfl_xor(esum, off);
        if (lane < TK) wp[lane] = e / esum;
    }
    asm volatile("s_waitcnt lgkmcnt(0)" ::: "memory");
}

// One wave per TWO adjacent q-rows (same head): row-1 load latency hides under
// row-0 work; bitonic chains interleaved (2x ILP); dual-row gather uses all 64
// lanes (lane half = row).
__global__ __launch_bounds__(256)
void topk_kernel(int voff, int ooff, int chunk)
{
    const float* V = g_ws + voff;
    float* O = g_ws + ooff;

    __shared__ unsigned long long sve[4][2][CAP];
    __shared__ float    wsel[4][2][32];
    __shared__ unsigned jsel[4][2][32];

    const int wid  = threadIdx.x >> 6;
    const int lane = threadIdx.x & 63;
    const int gr   = blockIdx.x * 4 + wid;     // pair index 0..8191
    const int row0 = gr * 2;
    const int zh   = row0 >> 11;               // 0..7
    const int q0   = row0 & 2047, q1 = q0 + 1;
    const int hh   = chunk * 8 + zh;
    const int b    = hh >> 2,  h = hh & 3;

    const float* Srow0 = g_sc + (size_t)zh * S_ * S_ + (size_t)q0 * S_;
    const float* Srow1 = Srow0 + S_;
    const float* vbase = V + (size_t)b * S_ * AD + h * HD;

    // ---- load + convert both rows ----
    unsigned keys0[32], keys1[32];
    unsigned lmax0 = 0u, lmax1 = 0u;
    #pragma unroll
    for (int i = 0; i < 8; ++i) {
        float4 s4 = ((const float4*)Srow0)[i * 64 + lane];
        unsigned k0 = f2key(s4.x), k1 = f2key(s4.y);
        unsigned k2 = f2key(s4.z), k3 = f2key(s4.w);
        keys0[i*4+0] = k0; keys0[i*4+1] = k1; keys0[i*4+2] = k2; keys0[i*4+3] = k3;
        unsigned m01 = (k0 > k1) ? k0 : k1, m23 = (k2 > k3) ? k2 : k3;
        unsigned m = (m01 > m23) ? m01 : m23;
        lmax0 = (m > lmax0) ? m : lmax0;
    }
    #pragma unroll
    for (int i = 0; i < 8; ++i) {
        float4 s4 = ((const float4*)Srow1)[i * 64 + lane];
        unsigned k0 = f2key(s4.x), k1 = f2key(s4.y);
        unsigned k2 = f2key(s4.z), k3 = f2key(s4.w);
        keys1[i*4+0] = k0; keys1[i*4+1] = k1; keys1[i*4+2] = k2; keys1[i*4+3] = k3;
        unsigned m01 = (k0 > k1) ? k0 : k1, m23 = (k2 > k3) ? k2 : k3;
        unsigned m = (m01 > m23) ? m01 : m23;
        lmax1 = (m > lmax1) ? m : lmax1;
    }

    // ---- interleaved bitonic sort (ascending) of lane maxima, both rows ----
    unsigned bs0 = lmax0, bs1 = lmax1;
    #pragma unroll
    for (int k = 2; k <= 64; k <<= 1) {
        #pragma unroll
        for (int j = k >> 1; j > 0; j >>= 1) {
            unsigned o0 = (unsigned)__shfl_xor((int)bs0, j);
            unsigned o1 = (unsigned)__shfl_xor((int)bs1, j);
            bool keepmin = (((lane & k) == 0) == ((lane & j) == 0));
            bs0 = keepmin ? (bs0 < o0 ? bs0 : o0) : (bs0 > o0 ? bs0 : o0);
            bs1 = keepmin ? (bs1 < o1 ? bs1 : o1) : (bs1 > o1 ? bs1 : o1);
        }
    }
    const unsigned thr0 = (unsigned)__shfl((int)bs0, 32);
    const unsigned thr1 = (unsigned)__shfl((int)bs1, 32);
    const float Mf0 = key2f((unsigned)__shfl((int)bs0, 63));
    const float Mf1 = key2f((unsigned)__shfl((int)bs1, 63));

    select_row(keys0, sve[wid][0], wsel[wid][0], jsel[wid][0], lane, thr0, Mf0);
    select_row(keys1, sve[wid][1], wsel[wid][1], jsel[wid][1], lane, thr1, Mf1);

    // ---- dual-row gather: half 0 -> row0, half 1 -> row1; dd = lane&31 ----
    const int dd = lane & 31, half = lane >> 5;
    const float*    wp = wsel[wid][half];
    const unsigned* jp = jsel[wid][half];
    float oacc = 0.f;
    #pragma unroll
    for (int i = 0; i < 32; ++i)
        oacc = fmaf(wp[i], vbase[(size_t)jp[i] * AD + dd], oacc);
    const int qq = half ? q1 : q0;
    O[((size_t)b * S_ + qq) * AD + h * HD + dd] = oacc;
}

__global__ __launch_bounds__(256)
void concat_kernel()
{
    int i = blockIdx.x * 256 + threadIdx.x;   // over 8192*256
    int row = i >> 8, c = i & 255;
    float v = (c < AD) ? g_ws[OFF_T + row * AD + c]
                       : g_ws[OFF_SB + row * AD + (c - AD)];
    g_ws[OFF_CAT + i] = v;
}

__global__ __launch_bounds__(256)
void fuse_kernel(float* __restrict__ out)
{
    int i = blockIdx.x * 256 + threadIdx.x;   // over 8192*128
    float g = g_ws[OFF_Q + i];
    float f = g_ws[OFF_K + i];
    out[i] = f / (1.0f + expf(-g));           // f * sigmoid(g)
}

extern "C" void kernel_launch(void* const* d_in, const int* in_sizes, int n_in,
                              void* d_out, int out_size, void* d_ws, size_t ws_size,
                              hipStream_t stream)
{
    (void)in_sizes; (void)n_in; (void)d_ws; (void)ws_size; (void)out_size;
    const float* x      = (const float*)d_in[0];
    const float* tp_w   = (const float*)d_in[1];
    const float* tp_b   = (const float*)d_in[2];
    const float* sp_w   = (const float*)d_in[3];
    const float* sp_b   = (const float*)d_in[4];
    const float* gate_w = (const float*)d_in[21];
    const float* gate_b = (const float*)d_in[22];
    const float* fus_w  = (const float*)d_in[23];
    const float* fus_b  = (const float*)d_in[24];

    dim3 gl(128, 2);
    for (int br = 0; br < 2; ++br) {
        const float* pw = br ? sp_w : tp_w;
        const float* pb = br ? sp_b : tp_b;
        int base = 5 + br * 8;
        const float* qw = (const float*)d_in[base + 0];
        const float* qb = (const float*)d_in[base + 1];
        const float* kw = (const float*)d_in[base + 2];
        const float* kb = (const float*)d_in[base + 3];
        const float* vw = (const float*)d_in[base + 4];
        const float* vb = (const float*)d_in[base + 5];
        const float* ow = (const float*)d_in[base + 6];
        const float* ob = (const float*)d_in[base + 7];

        lin_kernel<256><<<gl, 256, 0, stream>>>(x, 0, pw, pb, OFF_PROJ);
        lin3_kernel<128><<<dim3(128, 2, 3), 256, 0, stream>>>(
            OFF_PROJ, qw, qb, OFF_Q, kw, kb, OFF_K, vw, vb, OFF_V);
        for (int chunk = 0; chunk < 2; ++chunk) {
            score_kernel<<<dim3(32, 32, 8), 256, 0, stream>>>(OFF_Q, OFF_K, chunk);
            topk_kernel<<<2048, 256, 0, stream>>>(OFF_V, OFF_ATT, chunk);
        }
        lin_kernel<128><<<gl, 256, 0, stream>>>(nullptr, OFF_ATT, ow, ob,
                                                br ? OFF_SB : OFF_T);
    }
    concat_kernel<<<8192, 256, 0, stream>>>();
    lin3_kernel<256><<<dim3(128, 2, 2), 256, 0, stream>>>(
        OFF_CAT, gate_w, gate_b, OFF_Q, fus_w, fus_b, OFF_K,
        (const float*)nullptr, (const float*)nullptr, 0);
    fuse_kernel<<<4096, 256, 0, stream>>>((float*)d_out);
}